// Round 3
// baseline (14327.966 us; speedup 1.0000x reference)
//
#include <hip/hip_runtime.h>
#include <stdint.h>

typedef unsigned short u16;
typedef __attribute__((ext_vector_type(8))) short bf16x8;
typedef __attribute__((ext_vector_type(4))) float f32x4;
typedef __attribute__((ext_vector_type(4))) u16 u16x4;

__device__ __forceinline__ u16 f2bf(float f) {
  union { float f; uint32_t u; } v; v.f = f;
  uint32_t u = v.u;
  uint32_t r = u + 0x7fffu + ((u >> 16) & 1u);
  return (u16)(r >> 16);
}
__device__ __forceinline__ float bf2f(u16 h) {
  union { uint32_t u; float f; } v; v.u = ((uint32_t)h) << 16; return v.f;
}
__device__ __forceinline__ float sigm(float x) { return 1.f / (1.f + __expf(-x)); }
__device__ __forceinline__ float tanhfast(float x) {
  float t = __expf(-2.f * fabsf(x));
  float r = (1.f - t) / (1.f + t);
  return x < 0.f ? -r : r;
}

__global__ __launch_bounds__(256) void k_zero(float* __restrict__ p) {
  p[(size_t)blockIdx.x * 256 + threadIdx.x] = 0.f;
}

// Repack Wih||Whh (fp32) -> bf16 fragment-tiled: [l][jb(120)][k0(120)][g(4)][lane(64)][8]
// element: B[n = g*1920 + jb*16 + ln][k], k = k0*32 + quad*8 + jj; k0<60 -> Wih, else Whh
// total threads = 2*120*120*4*64 = 7,372,800  -> grid 28800 x 256
__global__ __launch_bounds__(256) void k_repB(const float* __restrict__ Wih,
                                              const float* __restrict__ Whh,
                                              u16* __restrict__ dst) {
  int e8 = blockIdx.x * 256 + threadIdx.x;       // one thread = 8 elements (jj)
  if (e8 >= 7372800) return;
  int lane = e8 & 63;
  int t1 = e8 >> 6;
  int g = t1 & 3;
  int t2 = t1 >> 2;
  int k0 = t2 % 120;
  int t3 = t2 / 120;
  int jb = t3 % 120;
  int l = t3 / 120;
  int ln = lane & 15, quad = lane >> 4;
  int n = g * 1920 + jb * 16 + ln;
  const float* src = (k0 < 60)
      ? (Wih + ((size_t)(l * 7680 + n)) * 1920 + k0 * 32 + quad * 8)
      : (Whh + ((size_t)(l * 7680 + n)) * 1920 + (k0 - 60) * 32 + quad * 8);
  float4 a = ((const float4*)src)[0];
  float4 b = ((const float4*)src)[1];
  u16x4 o0, o1;
  o0[0] = f2bf(a.x); o0[1] = f2bf(a.y); o0[2] = f2bf(a.z); o0[3] = f2bf(a.w);
  o1[0] = f2bf(b.x); o1[1] = f2bf(b.y); o1[2] = f2bf(b.z); o1[3] = f2bf(b.w);
  ((u16x4*)(dst + (size_t)e8 * 8))[0] = o0;
  ((u16x4*)(dst + (size_t)e8 * 8))[1] = o1;
}

// Repack W3 (fp32 [1920,1920]) -> [nb(30)][k0(60)][nt(4)][lane(64)][8]
// total threads = 30*60*4*64 = 460,800 -> grid 1800 x 256
__global__ __launch_bounds__(256) void k_repW3(const float* __restrict__ W3,
                                               u16* __restrict__ dst) {
  int e8 = blockIdx.x * 256 + threadIdx.x;
  if (e8 >= 460800) return;
  int lane = e8 & 63;
  int t1 = e8 >> 6;
  int nt = t1 & 3;
  int t2 = t1 >> 2;
  int k0 = t2 % 60;
  int nb = t2 / 60;
  int ln = lane & 15, quad = lane >> 4;
  int n = nb * 64 + nt * 16 + ln;
  const float* src = W3 + (size_t)n * 1920 + k0 * 32 + quad * 8;
  float4 a = ((const float4*)src)[0];
  float4 b = ((const float4*)src)[1];
  u16x4 o0, o1;
  o0[0] = f2bf(a.x); o0[1] = f2bf(a.y); o0[2] = f2bf(a.z); o0[3] = f2bf(a.w);
  o1[0] = f2bf(b.x); o1[1] = f2bf(b.y); o1[2] = f2bf(b.z); o1[3] = f2bf(b.w);
  ((u16x4*)(dst + (size_t)e8 * 8))[0] = o0;
  ((u16x4*)(dst + (size_t)e8 * 8))[1] = o1;
}

// ins-select + per-atom MLP; writes X into A0 x-part (fragment-tiled) and insb
__global__ __launch_bounds__(64) void k_mlp(
    const float* __restrict__ inputs, const float* __restrict__ prevb,
    const int* __restrict__ burn,
    const float* __restrict__ W1, const float* __restrict__ b1,
    const float* __restrict__ W2, const float* __restrict__ b2,
    u16* __restrict__ A0, float* __restrict__ insb, int t) {
  __shared__ float h1s[64];
  int ba = blockIdx.x;              // b*30 + a
  int b = ba / 30, a = ba % 30;
  int j = threadIdx.x;
  bool gt = (t <= *burn);
  const float* src = gt ? (inputs + (((size_t)ba) * 65 + t) * 4)
                        : (prevb + (size_t)ba * 4);
  float i0 = src[0], i1 = src[1], i2 = src[2], i3 = src[3];
  float h1 = b1[j] + i0 * W1[j * 4 + 0] + i1 * W1[j * 4 + 1] +
             i2 * W1[j * 4 + 2] + i3 * W1[j * 4 + 3];
  h1 = fmaxf(h1, 0.f);
  h1s[j] = h1;
  __syncthreads();
  float h2 = b2[j];
  const float* w2r = W2 + j * 64;
#pragma unroll 8
  for (int k = 0; k < 64; ++k) h2 += h1s[k] * w2r[k];
  h2 = fmaxf(h2, 0.f);
  // tiled write: m=b, k=a*64+j
  int mh = b >> 6, mloc = b & 63, mt = mloc >> 4, ln2 = mloc & 15;
  int ch = a * 2 + (j >> 5), quad2 = (j >> 3) & 3, jj = j & 7;
  size_t xi = ((size_t)(mh * 180 + ch) * 4 + mt) * 512 + (quad2 * 16 + ln2) * 8 + jj;
  A0[xi] = f2bf(h2);
  if (j < 4) insb[(size_t)ba * 4 + j] = src[j];
}

// Software-pipelined fragment GEMM core: NITER k-iters; iters < XITER read from ax,
// others from ah (offset rebased). One wave; 4 m-tiles x 4 n-tiles.
template <int NITER, int XITER>
__device__ __forceinline__ void gemm_pipe(const char* ax, const char* ah,
                                          const char* b, int lane_off,
                                          f32x4 acc[4][4]) {
  constexpr int D = 6;
  bf16x8 Af[D][4], Bf[D][4];
#pragma unroll
  for (int p = 0; p < D; ++p) {
    const char* ab = (p < XITER) ? (ax + (size_t)p * 4096)
                                 : (ah + (size_t)(p - XITER) * 4096);
    const char* bb = b + (size_t)p * 4096;
#pragma unroll
    for (int mt = 0; mt < 4; ++mt)
      Af[p][mt] = *(const bf16x8*)(ab + mt * 1024 + lane_off);
#pragma unroll
    for (int nt = 0; nt < 4; ++nt)
      Bf[p][nt] = *(const bf16x8*)(bb + nt * 1024 + lane_off);
  }
#pragma unroll
  for (int k = 0; k < NITER; ++k) {
    const int slot = k % D;
#pragma unroll
    for (int mt = 0; mt < 4; ++mt)
#pragma unroll
      for (int nt = 0; nt < 4; ++nt)
        acc[mt][nt] = __builtin_amdgcn_mfma_f32_16x16x32_bf16(
            Af[slot][mt], Bf[slot][nt], acc[mt][nt], 0, 0, 0);
    if (k + D < NITER) {
      const int kp = k + D;
      const char* ab = (kp < XITER) ? (ax + (size_t)kp * 4096)
                                    : (ah + (size_t)(kp - XITER) * 4096);
      const char* bb = b + (size_t)kp * 4096;
#pragma unroll
      for (int mt = 0; mt < 4; ++mt)
        Af[slot][mt] = *(const bf16x8*)(ab + mt * 1024 + lane_off);
#pragma unroll
      for (int nt = 0; nt < 4; ++nt)
        Bf[slot][nt] = *(const bf16x8*)(bb + nt * 1024 + lane_off);
    }
  }
}

// Gates GEMM + fused LSTM cell. grid(120 jb, 2 mh), 64 threads.
// n-tiles are gate-grouped: nt == gate (i,f,g,o), columns j = jb*16+ln.
__global__ __launch_bounds__(64) void k_gates(
    const u16* __restrict__ Atl, const u16* __restrict__ Brep_l,
    const float* __restrict__ bih_l, const float* __restrict__ bhh_l,
    float* __restrict__ c_l, u16* __restrict__ hA, u16* __restrict__ hB,
    int rd_off, int sB) {
  const int lane = threadIdx.x;
  const int jb = blockIdx.x;
  const int mh = blockIdx.y;
  const int lane_off = lane * 16;
  const char* ax = (const char*)Atl + (size_t)mh * 180 * 4096;
  const char* ah = ax + (size_t)rd_off * 4096;
  const char* b = (const char*)Brep_l + (size_t)jb * 120 * 4096;
  f32x4 acc[4][4] = {};
  gemm_pipe<120, 60>(ax, ah, b, lane_off, acc);

  const int ln = lane & 15, quad = lane >> 4;
  const int kh = jb * 16 + ln;                 // hidden index j
  const int chl = kh >> 5, quad2 = (kh >> 3) & 3, jj = kh & 7;
  float bs[4];
#pragma unroll
  for (int g = 0; g < 4; ++g) bs[g] = bih_l[g * 1920 + kh] + bhh_l[g * 1920 + kh];
#pragma unroll
  for (int mt = 0; mt < 4; ++mt) {
#pragma unroll
    for (int r = 0; r < 4; ++r) {
      int m = mh * 64 + mt * 16 + quad * 4 + r;
      float gi = acc[mt][0][r] + bs[0];
      float gf = acc[mt][1][r] + bs[1];
      float gg = acc[mt][2][r] + bs[2];
      float go = acc[mt][3][r] + bs[3];
      size_t ci = (size_t)m * 1920 + kh;
      float cn = sigm(gf) * c_l[ci] + sigm(gi) * tanhfast(gg);
      float hn = sigm(go) * tanhfast(cn);
      c_l[ci] = cn;
      u16 hb = f2bf(hn);
      int lane2 = quad2 * 16 + quad * 4 + r;
      size_t hi = ((size_t)(mh * 180 + chl) * 4 + mt) * 512 + lane2 * 8 + jj;
      hA[hi] = hb;
      size_t hi2 = ((size_t)(mh * sB + chl) * 4 + mt) * 512 + lane2 * 8 + jj;
      hB[hi2] = hb;
    }
  }
}

// W3 GEMM + relu -> plain bf16 [128,1920]. grid(30 nb, 2 mh).
__global__ __launch_bounds__(64) void k_w3(const u16* __restrict__ A2,
                                           const u16* __restrict__ W3r,
                                           const float* __restrict__ b3,
                                           u16* __restrict__ X3b) {
  const int lane = threadIdx.x;
  const int nb = blockIdx.x;
  const int mh = blockIdx.y;
  const int lane_off = lane * 16;
  const char* ax = (const char*)A2 + (size_t)mh * 60 * 4096;
  const char* b = (const char*)W3r + (size_t)nb * 60 * 4096;
  f32x4 acc[4][4] = {};
  gemm_pipe<60, 60>(ax, ax, b, lane_off, acc);
  const int ln = lane & 15, quad = lane >> 4;
#pragma unroll
  for (int nt = 0; nt < 4; ++nt) {
    int n = nb * 64 + nt * 16 + ln;
    float bias = b3[n];
#pragma unroll
    for (int mt = 0; mt < 4; ++mt)
#pragma unroll
      for (int r = 0; r < 4; ++r) {
        int m = mh * 64 + mt * 16 + quad * 4 + r;
        X3b[(size_t)m * 1920 + n] = f2bf(fmaxf(acc[mt][nt][r] + bias, 0.f));
      }
  }
}

// W4 projection + bias + residual; writes output slice t and prev-buffer
__global__ __launch_bounds__(64) void k_w4out(
    const u16* __restrict__ x3, const float* __restrict__ W4,
    const float* __restrict__ b4, const float* __restrict__ insb,
    float* __restrict__ outp, float* __restrict__ prevb, int t) {
  int m = blockIdx.x / 15;
  int pb = blockIdx.x % 15;
  int lane = threadIdx.x;
  const u16* xr = x3 + (size_t)m * 1920;
  float xv[30];
#pragma unroll
  for (int i = 0; i < 30; ++i) xv[i] = bf2f(xr[lane + 64 * i]);
#pragma unroll 1
  for (int pi = 0; pi < 8; ++pi) {
    int p = pb * 8 + pi;
    const float* wr = W4 + (size_t)p * 1920;
    float s = 0.f;
#pragma unroll
    for (int i = 0; i < 30; ++i) s += xv[i] * wr[lane + 64 * i];
#pragma unroll
    for (int off = 32; off > 0; off >>= 1) s += __shfl_xor(s, off);
    if (lane == 0) {
      float v = s + b4[p] + insb[(size_t)m * 120 + p];
      outp[(((size_t)m * 30 + (p >> 2)) * 64 + t) * 4 + (p & 3)] = v;
      prevb[(size_t)m * 120 + p] = v;
    }
  }
}

extern "C" void kernel_launch(void* const* d_in, const int* in_sizes, int n_in,
                              void* d_out, int out_size, void* d_ws, size_t ws_size,
                              hipStream_t stream) {
  (void)in_sizes; (void)n_in; (void)out_size;
  const float* inputs = (const float*)d_in[0];
  const float* W1 = (const float*)d_in[1];
  const float* b1 = (const float*)d_in[2];
  const float* W2 = (const float*)d_in[3];
  const float* b2 = (const float*)d_in[4];
  const float* Wih = (const float*)d_in[5];
  const float* Whh = (const float*)d_in[6];
  const float* bih = (const float*)d_in[7];
  const float* bhh = (const float*)d_in[8];
  const float* W3 = (const float*)d_in[9];
  const float* b3 = (const float*)d_in[10];
  const float* W4 = (const float*)d_in[11];
  const float* b4 = (const float*)d_in[12];
  const int* burn = (const int*)d_in[14];
  float* outp = (float*)d_out;
  char* ws = (char*)d_ws;

  // ---- workspace layout (bytes) ----
  // zero region: c (1966080) + A0 (1474560) + A1 (1474560) = 4915200
  float* cbuf = (float*)ws;                          // [2][128][1920] f32
  u16* A0 = (u16*)(ws + 1966080);                    // [2mh][180ch][4][512] u16
  u16* A1 = (u16*)(ws + 3440640);
  u16* A2 = (u16*)(ws + 4915200);                    // [2mh][60ch][4][512] u16
  u16* X3b = (u16*)(ws + 5406720);                   // [128][1920] bf16
  float* insb = (float*)(ws + 5898240);              // [128][120]
  float* prevb = (float*)(ws + 5959680);             // [128][120]
  u16* Brep = (u16*)(ws + 6021120);                  // 58982400 u16
  u16* W3r = (u16*)(ws + 123985920);                 // 3686400 u16
  if (ws_size < 131358720) return;                   // insufficient scratch

  // zero c + A0 + A1 (1228800 floats)
  hipLaunchKernelGGL(k_zero, dim3(4800), dim3(256), 0, stream, (float*)ws);
  // repack weights to bf16 fragment-tiled
  hipLaunchKernelGGL(k_repB, dim3(28800), dim3(256), 0, stream, Wih, Whh, Brep);
  hipLaunchKernelGGL(k_repW3, dim3(1800), dim3(256), 0, stream, W3, W3r);

  const size_t BrepL = (size_t)120 * 120 * 2048;     // per-layer elements

  for (int t = 0; t < 64; ++t) {
    int p = t & 1;
    int rd_off = 60 + p * 60;          // h chunks read this step
    int wr_off = 60 + (1 - p) * 60;    // h chunks written this step

    hipLaunchKernelGGL(k_mlp, dim3(3840), dim3(64), 0, stream,
                       inputs, prevb, burn, W1, b1, W2, b2, A0, insb, t);
    // layer 0: A=A0, writes h0 -> A0 h-part(wr) and A1 x-part (stride 180)
    hipLaunchKernelGGL(k_gates, dim3(120, 2), dim3(64), 0, stream,
                       A0, Brep, bih, bhh, cbuf,
                       A0 + (size_t)wr_off * 2048, A1, rd_off, 180);
    // layer 1: A=A1, writes h1 -> A1 h-part(wr) and A2 (stride 60)
    hipLaunchKernelGGL(k_gates, dim3(120, 2), dim3(64), 0, stream,
                       A1, Brep + BrepL, bih + 7680, bhh + 7680, cbuf + 245760,
                       A1 + (size_t)wr_off * 2048, A2, rd_off, 60);
    hipLaunchKernelGGL(k_w3, dim3(30, 2), dim3(64), 0, stream, A2, W3r, b3, X3b);
    hipLaunchKernelGGL(k_w4out, dim3(1920), dim3(64), 0, stream,
                       X3b, W4, b4, insb, outp, prevb, t);
  }
}

// Round 4
// 6097.079 us; speedup vs baseline: 2.3500x; 2.3500x over previous
//
#include <hip/hip_runtime.h>
#include <stdint.h>

typedef unsigned short u16;
typedef __attribute__((ext_vector_type(8))) short bf16x8;
typedef __attribute__((ext_vector_type(4))) float f32x4;
typedef __attribute__((ext_vector_type(4))) u16 u16x4;

__device__ __forceinline__ u16 f2bf(float f) {
  union { float f; uint32_t u; } v; v.f = f;
  uint32_t u = v.u;
  uint32_t r = u + 0x7fffu + ((u >> 16) & 1u);
  return (u16)(r >> 16);
}
__device__ __forceinline__ float bf2f(u16 h) {
  union { uint32_t u; float f; } v; v.u = ((uint32_t)h) << 16; return v.f;
}
__device__ __forceinline__ float sigm(float x) { return 1.f / (1.f + __expf(-x)); }
__device__ __forceinline__ float tanhfast(float x) {
  float t = __expf(-2.f * fabsf(x));
  float r = (1.f - t) / (1.f + t);
  return x < 0.f ? -r : r;
}

__global__ __launch_bounds__(256) void k_zero(float* __restrict__ p) {
  p[(size_t)blockIdx.x * 256 + threadIdx.x] = 0.f;
}

// Repack Wih||Whh (fp32) -> bf16 fragment-tiled: [l][jb(120)][k0(120)][g(4)][lane(64)][8]
// total threads = 2*120*120*4*64 = 7,372,800  -> grid 28800 x 256
__global__ __launch_bounds__(256) void k_repB(const float* __restrict__ Wih,
                                              const float* __restrict__ Whh,
                                              u16* __restrict__ dst) {
  int e8 = blockIdx.x * 256 + threadIdx.x;
  if (e8 >= 7372800) return;
  int lane = e8 & 63;
  int t1 = e8 >> 6;
  int g = t1 & 3;
  int t2 = t1 >> 2;
  int k0 = t2 % 120;
  int t3 = t2 / 120;
  int jb = t3 % 120;
  int l = t3 / 120;
  int ln = lane & 15, quad = lane >> 4;
  int n = g * 1920 + jb * 16 + ln;
  const float* src = (k0 < 60)
      ? (Wih + ((size_t)(l * 7680 + n)) * 1920 + k0 * 32 + quad * 8)
      : (Whh + ((size_t)(l * 7680 + n)) * 1920 + (k0 - 60) * 32 + quad * 8);
  float4 a = ((const float4*)src)[0];
  float4 b = ((const float4*)src)[1];
  u16x4 o0, o1;
  o0[0] = f2bf(a.x); o0[1] = f2bf(a.y); o0[2] = f2bf(a.z); o0[3] = f2bf(a.w);
  o1[0] = f2bf(b.x); o1[1] = f2bf(b.y); o1[2] = f2bf(b.z); o1[3] = f2bf(b.w);
  ((u16x4*)(dst + (size_t)e8 * 8))[0] = o0;
  ((u16x4*)(dst + (size_t)e8 * 8))[1] = o1;
}

// Repack W3 (fp32 [1920,1920]) -> [nb(30)][k0(60)][nt(4)][lane(64)][8]
// total threads = 30*60*4*64 = 460,800 -> grid 1800 x 256
__global__ __launch_bounds__(256) void k_repW3(const float* __restrict__ W3,
                                               u16* __restrict__ dst) {
  int e8 = blockIdx.x * 256 + threadIdx.x;
  if (e8 >= 460800) return;
  int lane = e8 & 63;
  int t1 = e8 >> 6;
  int nt = t1 & 3;
  int t2 = t1 >> 2;
  int k0 = t2 % 60;
  int nb = t2 / 60;
  int ln = lane & 15, quad = lane >> 4;
  int n = nb * 64 + nt * 16 + ln;
  const float* src = W3 + (size_t)n * 1920 + k0 * 32 + quad * 8;
  float4 a = ((const float4*)src)[0];
  float4 b = ((const float4*)src)[1];
  u16x4 o0, o1;
  o0[0] = f2bf(a.x); o0[1] = f2bf(a.y); o0[2] = f2bf(a.z); o0[3] = f2bf(a.w);
  o1[0] = f2bf(b.x); o1[1] = f2bf(b.y); o1[2] = f2bf(b.z); o1[3] = f2bf(b.w);
  ((u16x4*)(dst + (size_t)e8 * 8))[0] = o0;
  ((u16x4*)(dst + (size_t)e8 * 8))[1] = o1;
}

// ins-select + per-atom MLP; writes X into A0 x-part (fragment-tiled) and insb
__global__ __launch_bounds__(64) void k_mlp(
    const float* __restrict__ inputs, const float* __restrict__ prevb,
    const int* __restrict__ burn,
    const float* __restrict__ W1, const float* __restrict__ b1,
    const float* __restrict__ W2, const float* __restrict__ b2,
    u16* __restrict__ A0, float* __restrict__ insb, int t) {
  __shared__ float h1s[64];
  int ba = blockIdx.x;              // b*30 + a
  int b = ba / 30, a = ba % 30;
  int j = threadIdx.x;
  bool gt = (t <= *burn);
  const float* src = gt ? (inputs + (((size_t)ba) * 65 + t) * 4)
                        : (prevb + (size_t)ba * 4);
  float i0 = src[0], i1 = src[1], i2 = src[2], i3 = src[3];
  float h1 = b1[j] + i0 * W1[j * 4 + 0] + i1 * W1[j * 4 + 1] +
             i2 * W1[j * 4 + 2] + i3 * W1[j * 4 + 3];
  h1 = fmaxf(h1, 0.f);
  h1s[j] = h1;
  __syncthreads();
  float h2 = b2[j];
  const float* w2r = W2 + j * 64;
#pragma unroll 8
  for (int k = 0; k < 64; ++k) h2 += h1s[k] * w2r[k];
  h2 = fmaxf(h2, 0.f);
  // tiled write: m=b, k=a*64+j
  int mh = b >> 6, mloc = b & 63, mt = mloc >> 4, ln2 = mloc & 15;
  int ch = a * 2 + (j >> 5), quad2 = (j >> 3) & 3, jj = j & 7;
  size_t xi = ((size_t)(mh * 180 + ch) * 4 + mt) * 512 + (quad2 * 16 + ln2) * 8 + jj;
  A0[xi] = f2bf(h2);
  if (j < 4) insb[(size_t)ba * 4 + j] = src[j];
}

// Rolling-pipeline fragment GEMM: ITERS k-iters (32 k each), depth 5.
// All slot indices compile-time (inner loops fully unrolled, outer dynamic).
// Requires (ITERS-5) % 5 == 0.
template <int ITERS>
__device__ __forceinline__ void gemm_pipe(const char* __restrict__ aw,
                                          const char* __restrict__ bw,
                                          int lane_off, f32x4 acc[4][4]) {
  constexpr int D = 5;
  bf16x8 Af[D][4], Bf[D][4];
#pragma unroll
  for (int p = 0; p < D; ++p) {
#pragma unroll
    for (int mt = 0; mt < 4; ++mt)
      Af[p][mt] = *(const bf16x8*)(aw + p * 4096 + mt * 1024 + lane_off);
#pragma unroll
    for (int nt = 0; nt < 4; ++nt)
      Bf[p][nt] = *(const bf16x8*)(bw + p * 4096 + nt * 1024 + lane_off);
  }
  for (int o = 0; o < (ITERS - D) / D; ++o) {
    const char* ap = aw + (size_t)(o + 1) * (D * 4096);
    const char* bp = bw + (size_t)(o + 1) * (D * 4096);
#pragma unroll
    for (int d = 0; d < D; ++d) {
#pragma unroll
      for (int mt = 0; mt < 4; ++mt)
#pragma unroll
        for (int nt = 0; nt < 4; ++nt)
          acc[mt][nt] = __builtin_amdgcn_mfma_f32_16x16x32_bf16(
              Af[d][mt], Bf[d][nt], acc[mt][nt], 0, 0, 0);
#pragma unroll
      for (int mt = 0; mt < 4; ++mt)
        Af[d][mt] = *(const bf16x8*)(ap + d * 4096 + mt * 1024 + lane_off);
#pragma unroll
      for (int nt = 0; nt < 4; ++nt)
        Bf[d][nt] = *(const bf16x8*)(bp + d * 4096 + nt * 1024 + lane_off);
    }
  }
#pragma unroll
  for (int d = 0; d < D; ++d) {
#pragma unroll
    for (int mt = 0; mt < 4; ++mt)
#pragma unroll
      for (int nt = 0; nt < 4; ++nt)
        acc[mt][nt] = __builtin_amdgcn_mfma_f32_16x16x32_bf16(
            Af[d][mt], Bf[d][nt], acc[mt][nt], 0, 0, 0);
  }
}

// Gates GEMM + fused LSTM cell. grid(120 jb, 2 mh) x 256 threads (4 waves).
// Wave w computes K-chunk w (30 of 120 k-iters); LDS reduce; wave w applies
// the cell to m-tile w. n-tiles are gate-grouped: nt == gate (i,f,g,o).
__global__ __launch_bounds__(256, 1) void k_gates(
    const u16* __restrict__ Atl, const u16* __restrict__ Brep_l,
    const float* __restrict__ bih_l, const float* __restrict__ bhh_l,
    float* __restrict__ c_l, u16* __restrict__ hA, u16* __restrict__ hB,
    int rd_off, int sB) {
  __shared__ float red[4][4][16][64];   // [p][nt][ln][m_local] = 64 KB
  const int tid = threadIdx.x;
  const int w = tid >> 6;
  const int lane = tid & 63;
  const int ln = lane & 15, quad = lane >> 4;
  const int jb = blockIdx.x;
  const int mh = blockIdx.y;
  const int lane_off = lane * 16;

  const char* ax = (const char*)Atl + (size_t)mh * 180 * 4096;
  const char* ah = ax + (size_t)rd_off * 4096;
  const char* aw = (w < 2) ? (ax + (size_t)(30 * w) * 4096)
                           : (ah + (size_t)(30 * (w - 2)) * 4096);
  const char* bw = (const char*)Brep_l + ((size_t)jb * 120 + 30 * w) * 4096;

  f32x4 acc[4][4] = {};
  gemm_pipe<30>(aw, bw, lane_off, acc);

  // stage partials: [w][nt][ln][mt*16+quad*4 .. +3]
#pragma unroll
  for (int mt = 0; mt < 4; ++mt)
#pragma unroll
    for (int nt = 0; nt < 4; ++nt)
      *(f32x4*)&red[w][nt][ln][mt * 16 + quad * 4] = acc[mt][nt];
  __syncthreads();

  // wave w reduces + cell for m-tile w
  f32x4 g[4];
#pragma unroll
  for (int nt = 0; nt < 4; ++nt) {
    f32x4 s = *(const f32x4*)&red[0][nt][ln][w * 16 + quad * 4];
#pragma unroll
    for (int p = 1; p < 4; ++p) {
      f32x4 tv = *(const f32x4*)&red[p][nt][ln][w * 16 + quad * 4];
      s[0] += tv[0]; s[1] += tv[1]; s[2] += tv[2]; s[3] += tv[3];
    }
    g[nt] = s;
  }

  const int kh = jb * 16 + ln;                 // hidden index j
  const int chl = kh >> 5, quad2 = (kh >> 3) & 3, jj = kh & 7;
  float bs[4];
#pragma unroll
  for (int gi = 0; gi < 4; ++gi) bs[gi] = bih_l[gi * 1920 + kh] + bhh_l[gi * 1920 + kh];
#pragma unroll
  for (int r = 0; r < 4; ++r) {
    int m = mh * 64 + w * 16 + quad * 4 + r;
    float vi = g[0][r] + bs[0];
    float vf = g[1][r] + bs[1];
    float vg = g[2][r] + bs[2];
    float vo = g[3][r] + bs[3];
    size_t ci = (size_t)m * 1920 + kh;
    float cn = sigm(vf) * c_l[ci] + sigm(vi) * tanhfast(vg);
    float hn = sigm(vo) * tanhfast(cn);
    c_l[ci] = cn;
    u16 hb = f2bf(hn);
    int lane2 = quad2 * 16 + quad * 4 + r;
    size_t hi = ((size_t)(mh * 180 + chl) * 4 + w) * 512 + lane2 * 8 + jj;
    hA[hi] = hb;
    size_t hi2 = ((size_t)(mh * sB + chl) * 4 + w) * 512 + lane2 * 8 + jj;
    hB[hi2] = hb;
  }
}

// W3 GEMM + relu -> plain bf16 [128,1920]. grid(30 nb, 2 mh) x 256 (4-wave K-split).
__global__ __launch_bounds__(256, 1) void k_w3(const u16* __restrict__ A2,
                                               const u16* __restrict__ W3r,
                                               const float* __restrict__ b3,
                                               u16* __restrict__ X3b) {
  __shared__ float red[4][4][16][64];
  const int tid = threadIdx.x;
  const int w = tid >> 6;
  const int lane = tid & 63;
  const int ln = lane & 15, quad = lane >> 4;
  const int nb = blockIdx.x;
  const int mh = blockIdx.y;
  const int lane_off = lane * 16;

  const char* aw = (const char*)A2 + ((size_t)mh * 60 + 15 * w) * 4096;
  const char* bw = (const char*)W3r + ((size_t)nb * 60 + 15 * w) * 4096;

  f32x4 acc[4][4] = {};
  gemm_pipe<15>(aw, bw, lane_off, acc);

#pragma unroll
  for (int mt = 0; mt < 4; ++mt)
#pragma unroll
    for (int nt = 0; nt < 4; ++nt)
      *(f32x4*)&red[w][nt][ln][mt * 16 + quad * 4] = acc[mt][nt];
  __syncthreads();

#pragma unroll
  for (int nt = 0; nt < 4; ++nt) {
    f32x4 s = *(const f32x4*)&red[0][nt][ln][w * 16 + quad * 4];
#pragma unroll
    for (int p = 1; p < 4; ++p) {
      f32x4 tv = *(const f32x4*)&red[p][nt][ln][w * 16 + quad * 4];
      s[0] += tv[0]; s[1] += tv[1]; s[2] += tv[2]; s[3] += tv[3];
    }
    int n = nb * 64 + nt * 16 + ln;
    float bias = b3[n];
#pragma unroll
    for (int r = 0; r < 4; ++r) {
      int m = mh * 64 + w * 16 + quad * 4 + r;
      X3b[(size_t)m * 1920 + n] = f2bf(fmaxf(s[r] + bias, 0.f));
    }
  }
}

// W4 projection + bias + residual; writes output slice t and prev-buffer
__global__ __launch_bounds__(64) void k_w4out(
    const u16* __restrict__ x3, const float* __restrict__ W4,
    const float* __restrict__ b4, const float* __restrict__ insb,
    float* __restrict__ outp, float* __restrict__ prevb, int t) {
  int m = blockIdx.x / 15;
  int pb = blockIdx.x % 15;
  int lane = threadIdx.x;
  const u16* xr = x3 + (size_t)m * 1920;
  float xv[30];
#pragma unroll
  for (int i = 0; i < 30; ++i) xv[i] = bf2f(xr[lane + 64 * i]);
#pragma unroll 1
  for (int pi = 0; pi < 8; ++pi) {
    int p = pb * 8 + pi;
    const float* wr = W4 + (size_t)p * 1920;
    float s = 0.f;
#pragma unroll
    for (int i = 0; i < 30; ++i) s += xv[i] * wr[lane + 64 * i];
#pragma unroll
    for (int off = 32; off > 0; off >>= 1) s += __shfl_xor(s, off);
    if (lane == 0) {
      float v = s + b4[p] + insb[(size_t)m * 120 + p];
      outp[(((size_t)m * 30 + (p >> 2)) * 64 + t) * 4 + (p & 3)] = v;
      prevb[(size_t)m * 120 + p] = v;
    }
  }
}

extern "C" void kernel_launch(void* const* d_in, const int* in_sizes, int n_in,
                              void* d_out, int out_size, void* d_ws, size_t ws_size,
                              hipStream_t stream) {
  (void)in_sizes; (void)n_in; (void)out_size;
  const float* inputs = (const float*)d_in[0];
  const float* W1 = (const float*)d_in[1];
  const float* b1 = (const float*)d_in[2];
  const float* W2 = (const float*)d_in[3];
  const float* b2 = (const float*)d_in[4];
  const float* Wih = (const float*)d_in[5];
  const float* Whh = (const float*)d_in[6];
  const float* bih = (const float*)d_in[7];
  const float* bhh = (const float*)d_in[8];
  const float* W3 = (const float*)d_in[9];
  const float* b3 = (const float*)d_in[10];
  const float* W4 = (const float*)d_in[11];
  const float* b4 = (const float*)d_in[12];
  const int* burn = (const int*)d_in[14];
  float* outp = (float*)d_out;
  char* ws = (char*)d_ws;

  // ---- workspace layout (bytes) ----
  // zero region: c (1966080) + A0 (1474560) + A1 (1474560) = 4915200
  float* cbuf = (float*)ws;                          // [2][128][1920] f32
  u16* A0 = (u16*)(ws + 1966080);                    // [2mh][180ch][4][512] u16
  u16* A1 = (u16*)(ws + 3440640);
  u16* A2 = (u16*)(ws + 4915200);                    // [2mh][60ch][4][512] u16
  u16* X3b = (u16*)(ws + 5406720);                   // [128][1920] bf16
  float* insb = (float*)(ws + 5898240);              // [128][120]
  float* prevb = (float*)(ws + 5959680);             // [128][120]
  u16* Brep = (u16*)(ws + 6021120);                  // 58982400 u16
  u16* W3r = (u16*)(ws + 123985920);                 // 3686400 u16
  if (ws_size < 131358720) return;                   // insufficient scratch

  // zero c + A0 + A1 (1228800 floats)
  hipLaunchKernelGGL(k_zero, dim3(4800), dim3(256), 0, stream, (float*)ws);
  // repack weights to bf16 fragment-tiled
  hipLaunchKernelGGL(k_repB, dim3(28800), dim3(256), 0, stream, Wih, Whh, Brep);
  hipLaunchKernelGGL(k_repW3, dim3(1800), dim3(256), 0, stream, W3, W3r);

  const size_t BrepL = (size_t)120 * 120 * 2048;     // per-layer elements

  for (int t = 0; t < 64; ++t) {
    int p = t & 1;
    int rd_off = 60 + p * 60;          // h chunks read this step
    int wr_off = 60 + (1 - p) * 60;    // h chunks written this step

    hipLaunchKernelGGL(k_mlp, dim3(3840), dim3(64), 0, stream,
                       inputs, prevb, burn, W1, b1, W2, b2, A0, insb, t);
    // layer 0: A=A0, writes h0 -> A0 h-part(wr) and A1 x-part (stride 180)
    hipLaunchKernelGGL(k_gates, dim3(120, 2), dim3(256), 0, stream,
                       A0, Brep, bih, bhh, cbuf,
                       A0 + (size_t)wr_off * 2048, A1, rd_off, 180);
    // layer 1: A=A1, writes h1 -> A1 h-part(wr) and A2 (stride 60)
    hipLaunchKernelGGL(k_gates, dim3(120, 2), dim3(256), 0, stream,
                       A1, Brep + BrepL, bih + 7680, bhh + 7680, cbuf + 245760,
                       A1 + (size_t)wr_off * 2048, A2, rd_off, 60);
    hipLaunchKernelGGL(k_w3, dim3(30, 2), dim3(256), 0, stream, A2, W3r, b3, X3b);
    hipLaunchKernelGGL(k_w4out, dim3(1920), dim3(64), 0, stream,
                       X3b, W4, b4, insb, outp, prevb, t);
  }
}